// Round 14
// baseline (199.887 us; speedup 1.0000x reference)
//
#include <hip/hip_runtime.h>
#include <stdint.h>

#define BB 6
#define NPTS 1024
#define DD 128
#define HH 320
#define WW 320
#define NC 500
#define HWsz (HH*WW)
#define CAP 2048
#define NBLK ((HH/8)*(WW/8))
#define TX 32
#define TY 8
#define NSLOT 64
// accs: 7 quantities x 64 slots, each slot on its own 64B line
// q: 0=distinction 1=bce 2=extra 3=pos 4=neg 5=pcnt 6=ncnt

typedef __attribute__((ext_vector_type(8))) short bf16x8;
typedef __attribute__((ext_vector_type(4))) float f32x4;

__device__ __forceinline__ int clampi(int v, int lo, int hi){ return v<lo?lo:(v>hi?hi:v); }
__device__ __forceinline__ int refl(int p, int L){ if(p<0)p=-p; if(p>=L)p=2*L-2-p; return p; }

__device__ __forceinline__ float wave_sum(float v){
  #pragma unroll
  for (int o = 32; o > 0; o >>= 1) v += __shfl_xor(v, o, 64);
  return v;
}
__device__ __forceinline__ double wave_sumd(double v){
  #pragma unroll
  for (int o = 32; o > 0; o >>= 1) v += __shfl_xor(v, o, 64);
  return v;
}
__device__ __forceinline__ float wave_max(float v){
  #pragma unroll
  for (int o = 32; o > 0; o >>= 1) v = fmaxf(v, __shfl_xor(v, o, 64));
  return v;
}

__device__ __constant__ float GW[7] = {
  0.0044330481f, 0.0540055850f, 0.2420362300f, 0.3990502700f,
  0.2420362300f, 0.0540055850f, 0.0044330481f };

// ---------------- projection (matches pairwise_project) ----------------
struct Proj { float u, v; int vis; };

__device__ Proj project_point(float ptx, float pty, int jsrc, int itgt,
                              const float* __restrict__ depths,
                              const float* __restrict__ poses,
                              const float* __restrict__ Km)
{
  float pxx = ((ptx + 1.0f)*(float)(WW-1))*0.5f;
  float pxy = ((pty + 1.0f)*(float)(HH-1))*0.5f;
  float rx = rintf(pxx), ry = rintf(pxy);
  rx = fminf(fmaxf(rx, 0.f), (float)(WW-1));
  ry = fminf(fmaxf(ry, 0.f), (float)(HH-1));
  int xi = (int)rx, yi = (int)ry;
  float d = depths[(size_t)jsrc*HWsz + yi*WW + xi];
  float a00=Km[0],a01=Km[1],a02=Km[2],a10=Km[3],a11=Km[4],a12=Km[5],a20=Km[6],a21=Km[7],a22=Km[8];
  float det = a00*(a11*a22 - a12*a21) - a01*(a10*a22 - a12*a20) + a02*(a10*a21 - a11*a20);
  float id_ = 1.0f/det;
  float i00 = (a11*a22 - a12*a21)*id_;
  float i01 = (a02*a21 - a01*a22)*id_;
  float i02 = (a01*a12 - a02*a11)*id_;
  float i10 = (a12*a20 - a10*a22)*id_;
  float i11 = (a00*a22 - a02*a20)*id_;
  float i12 = (a02*a10 - a00*a12)*id_;
  float i20 = (a10*a21 - a11*a20)*id_;
  float i21 = (a01*a20 - a00*a21)*id_;
  float i22 = (a00*a11 - a01*a10)*id_;
  float c0 = (i00*pxx + i01*pxy + i02)*d;
  float c1 = (i10*pxx + i11*pxy + i12)*d;
  float c2 = (i20*pxx + i21*pxy + i22)*d;
  const float* Pj = poses + (size_t)jsrc*16;
  float w0 = Pj[0]*c0 + Pj[1]*c1 + Pj[2]*c2  + Pj[3];
  float w1 = Pj[4]*c0 + Pj[5]*c1 + Pj[6]*c2  + Pj[7];
  float w2 = Pj[8]*c0 + Pj[9]*c1 + Pj[10]*c2 + Pj[11];
  const float* Pi = poses + (size_t)itgt*16;
  float dx = w0 - Pi[3], dy = w1 - Pi[7], dz = w2 - Pi[11];
  float e0 = Pi[0]*dx + Pi[4]*dy + Pi[8]*dz;
  float e1 = Pi[1]*dx + Pi[5]*dy + Pi[9]*dz;
  float e2 = Pi[2]*dx + Pi[6]*dy + Pi[10]*dz;
  float uu = a00*e0 + a01*e1 + a02*e2;
  float vv = a10*e0 + a11*e1 + a12*e2;
  float zz = a20*e0 + a21*e1 + a22*e2;
  float zs = (fabsf(zz) > 1e-6f) ? zz : 1e-6f;
  Proj r;
  r.u = uu/zs; r.v = vv/zs;
  r.vis = (zz > 0.1f) && (r.u >= 0.f) && (r.u <= (float)(WW-1)) && (r.v >= 0.f) && (r.v <= (float)(HH-1));
  return r;
}

// ---------------- K1: FUSED gftt (blocks < 2400) + rownorm/proj (blocks >= 2400) ----------------
__global__ __launch_bounds__(256) void k_gftt(const float* __restrict__ imgs,
        float* __restrict__ resp,
        const float* __restrict__ desc, float* __restrict__ xx, unsigned short* __restrict__ dbf,
        const float* __restrict__ points, const float* __restrict__ depths,
        const float* __restrict__ poses, const float* __restrict__ Km,
        float* __restrict__ mproj, unsigned char* __restrict__ mvis){
  __shared__ float lg[TY+8][TX+8];
  __shared__ float lxx[TY+6][TX+6], lyy[TY+6][TX+6], lxy[TY+6][TX+6];
  int fb = blockIdx.x;
  if (fb >= 2400){
    // ---- rownorm + bf16 convert + point projection ----
    int t = (fb - 2400)*256 + threadIdx.x;
    if (t < BB*NPTS){
      const float* dptr = desc + (size_t)t*DD;
      unsigned short* optr = dbf + (size_t)t*DD;
      float s = 0.f;
      for (int d = 0; d < DD; d += 4){
        float4 v = *(const float4*)(dptr + d);
        s += v.x*v.x + v.y*v.y + v.z*v.z + v.w*v.w;
        unsigned int u0 = __float_as_uint(v.x); optr[d+0] = (unsigned short)((u0 + 0x7fffu + ((u0>>16)&1u)) >> 16);
        unsigned int u1 = __float_as_uint(v.y); optr[d+1] = (unsigned short)((u1 + 0x7fffu + ((u1>>16)&1u)) >> 16);
        unsigned int u2 = __float_as_uint(v.z); optr[d+2] = (unsigned short)((u2 + 0x7fffu + ((u2>>16)&1u)) >> 16);
        unsigned int u3 = __float_as_uint(v.w); optr[d+3] = (unsigned short)((u3 + 0x7fffu + ((u3>>16)&1u)) >> 16);
      }
      xx[t] = s;
      return;
    }
    int t2 = t - BB*NPTS;
    if (t2 >= BB*BB*NPTS) return;
    int i = t2 / (BB*NPTS); int r = t2 - i*(BB*NPTS); int j = r / NPTS; int n = r - j*NPTS;
    float ptx = points[((size_t)j*NPTS+n)*2+0];
    float pty = points[((size_t)j*NPTS+n)*2+1];
    Proj pr = project_point(ptx, pty, j, i, depths, poses, Km);
    mproj[(size_t)t2*2+0] = (pr.u*2.0f)/(float)(WW-1) - 1.0f;
    mproj[(size_t)t2*2+1] = (pr.v*2.0f)/(float)(HH-1) - 1.0f;
    mvis[t2] = pr.vis ? 1 : 0;
    return;
  }
  int b = fb / 400; int rem = fb - b*400;
  int by = rem / 10, bx = rem - by*10;
  int x0 = bx*TX, y0 = by*TY;
  const float* br = imgs + (size_t)b*3*HWsz;
  const float* bg = br + HWsz;
  const float* bbl = bg + HWsz;
  const int GW2 = TX+8, GH2 = TY+8;
  for (int i = threadIdx.x; i < GH2*GW2; i += 256){
    int ly = i / GW2, lx = i - ly*GW2;
    int gy = clampi(y0-4+ly, 0, HH-1), gx = clampi(x0-4+lx, 0, WW-1);
    size_t off = (size_t)gy*WW + gx;
    lg[ly][lx] = 0.299f*br[off] + 0.587f*bg[off] + 0.114f*bbl[off];
  }
  __syncthreads();
  const int PW2 = TX+6, PH2 = TY+6;
  for (int i = threadIdx.x; i < PH2*PW2; i += 256){
    int ly = i / PW2, lx = i - ly*PW2;
    int pcy = refl(y0-3+ly, HH), pcx = refl(x0-3+lx, WW);
    int ym = clampi(pcy-1,0,HH-1)-(y0-4), yc = pcy-(y0-4), yp = clampi(pcy+1,0,HH-1)-(y0-4);
    int xm = clampi(pcx-1,0,WW-1)-(x0-4), xc = pcx-(x0-4), xp = clampi(pcx+1,0,WW-1)-(x0-4);
    float g00=lg[ym][xm], g01=lg[ym][xc], g02=lg[ym][xp];
    float g10=lg[yc][xm],                 g12=lg[yc][xp];
    float g20=lg[yp][xm], g21=lg[yp][xc], g22=lg[yp][xp];
    float gx = 0.125f*(g02-g00)+0.25f*(g12-g10)+0.125f*(g22-g20);
    float gy = 0.125f*(g20-g00)+0.25f*(g21-g01)+0.125f*(g22-g02);
    lxx[ly][lx]=gx*gx; lyy[ly][lx]=gy*gy; lxy[ly][lx]=gx*gy;
  }
  __syncthreads();
  int tx = threadIdx.x & (TX-1), ty = threadIdx.x / TX;
  float sxx=0.f, syy=0.f, sxy=0.f;
  #pragma unroll
  for (int i=0;i<7;++i){
    float wr = GW[i];
    #pragma unroll
    for (int j=0;j<7;++j){
      float wc = wr*GW[j];
      sxx += wc*lxx[ty+i][tx+j];
      syy += wc*lyy[ty+i][tx+j];
      sxy += wc*lxy[ty+i][tx+j];
    }
  }
  float tr = sxx+syy, df = sxx-syy;
  float disc = sqrtf(fmaxf(df*df + 4.f*sxy*sxy, 0.f));
  resp[(size_t)b*HWsz + (size_t)(y0+ty)*WW + (x0+tx)] = 0.5f*(tr - disc);
}

// ---------------- K4+K5 fused: 5x5 NMS + 8x8 blockmax + slot write ----------------
__global__ __launch_bounds__(256) void k_nmsblk(const float* __restrict__ resp,
        unsigned long long* __restrict__ ckeys, unsigned int* __restrict__ ccnt){
  __shared__ float lr[TY+4][TX+4];
  __shared__ float lk[TY][TX];
  int b = blockIdx.z;
  int x0 = blockIdx.x*TX, y0 = blockIdx.y*TY;
  const float* rb = resp + (size_t)b*HWsz;
  const int W2 = TX+4, H2 = TY+4;
  for (int i = threadIdx.x; i < H2*W2; i += 256){
    int ly = i / W2, lx = i - ly*W2;
    int gy = y0 - 2 + ly, gx = x0 - 2 + lx;
    lr[ly][lx] = (gy >= 0 && gy < HH && gx >= 0 && gx < WW) ? rb[(size_t)gy*WW + gx] : -1e30f;
  }
  __syncthreads();
  int tx = threadIdx.x & (TX-1), ty = threadIdx.x / TX;
  float m = -1e30f;
  #pragma unroll
  for (int dy=0; dy<5; ++dy)
    #pragma unroll
    for (int dx=0; dx<5; ++dx) m = fmaxf(m, lr[ty+dy][tx+dx]);
  float r = lr[ty+2][tx+2];
  lk[ty][tx] = (r == m) ? r : 0.f;
  __syncthreads();
  int wave = threadIdx.x >> 6, lane = threadIdx.x & 63;
  int ly = lane >> 3, lx = wave*8 + (lane & 7);
  float v = lk[ly][lx];
  float bm = wave_max(v);
  if (!(bm > 0.f)) return;
  unsigned long long mask = __ballot(v == bm);
  if (v == bm){
    int yy = y0 + ly, xx2 = x0 + lx;
    unsigned long long key =
      ((unsigned long long)__float_as_uint(bm) << 32) |
      (unsigned long long)(0xFFFFFFFFu - (unsigned int)(yy*WW + xx2));
    int rank = __popcll(mask & ((1ull << lane) - 1ull));
    int rblk = blockIdx.y*(WW/8) + blockIdx.x*4 + wave;
    if (rank == 0){
      ckeys[(size_t)b*CAP + rblk] = key;
    } else {
      unsigned int slot = NBLK + atomicAdd(&ccnt[b], 1u);
      if (slot < CAP) ckeys[(size_t)b*CAP + slot] = key;
    }
  }
}

// ---------------- K6: bitonic top-500 per batch ----------------
__global__ __launch_bounds__(1024) void k_top500(const unsigned long long* __restrict__ ckeys,
        float* __restrict__ cpts, float* __restrict__ cvals){
  __shared__ unsigned long long sk[CAP];
  int b = blockIdx.x;
  int tid = threadIdx.x;
  for (int i = tid; i < CAP; i += 1024)
    sk[i] = ckeys[(size_t)b*CAP + i];
  __syncthreads();
  for (int k = 2; k <= CAP; k <<= 1){
    for (int j = k >> 1; j > 0; j >>= 1){
      for (int i = tid; i < CAP; i += 1024){
        int l = i ^ j;
        if (l > i){
          unsigned long long A = sk[i], Bv = sk[l];
          bool up = ((i & k) == 0);
          if ((A > Bv) == up){ sk[i] = Bv; sk[l] = A; }
        }
      }
      __syncthreads();
    }
  }
  if (tid < NC){
    unsigned long long key = sk[CAP-1-tid];
    float val = __uint_as_float((unsigned int)(key >> 32));
    size_t o = (size_t)b*NC + tid;
    if (val > 0.f){
      unsigned int idx = 0xFFFFFFFFu - (unsigned int)(key & 0xFFFFFFFFull);
      float fx = (float)(idx % WW), fy = (float)(idx / WW);
      cpts[o*2+0] = (fx*2.0f)/(float)(WW-1) - 1.0f;
      cpts[o*2+1] = (fy*2.0f)/(float)(HH-1) - 1.0f;
      cvals[o] = val;
    } else {
      cpts[o*2+0] = __int_as_float(0x7fc00000);
      cpts[o*2+1] = __int_as_float(0x7fc00000);
      cvals[o] = 0.f;
    }
  }
}

// ---------------- K7: corner projection + scatter-max ----------------
__global__ void k_corner_scatter(const float* __restrict__ cpts, const float* __restrict__ cvals,
        const float* __restrict__ depths, const float* __restrict__ poses,
        const float* __restrict__ Km, unsigned int* __restrict__ target){
  int t = blockIdx.x*blockDim.x + threadIdx.x;
  if (t >= BB*BB*NC) return;
  int i = t / (BB*NC); int r = t - i*(BB*NC); int j = r / NC; int n = r - j*NC;
  float val = cvals[(size_t)i*NC + n];
  float ptx = cpts[((size_t)j*NC+n)*2+0];
  float pty = cpts[((size_t)j*NC+n)*2+1];
  if (!(val > 0.f) || ptx != ptx) return;
  Proj pr = project_point(ptx, pty, j, i, depths, poses, Km);
  if (!pr.vis) return;
  float nu = (pr.u*2.0f)/(float)(WW-1) - 1.0f;
  float nv = (pr.v*2.0f)/(float)(HH-1) - 1.0f;
  float px2 = ((nu+1.0f)*(float)(WW-1))*0.5f;
  float py2 = ((nv+1.0f)*(float)(HH-1))*0.5f;
  float rx = rintf(px2), ry = rintf(py2);
  if (!(rx >= 0.f && ry >= 0.f && rx <= (float)(WW-1) && ry <= (float)(HH-1))) return;
  int wf = (int)rx, hf = (int)ry;
  atomicMax(&target[(size_t)j*HWsz + hf*WW + wf], __float_as_uint(val));
}

// ---------------- K8: target NMS + BCE + laplacian, LDS-tiled + slot atomics ----------------
__global__ __launch_bounds__(256) void k_score_reduce(const float* __restrict__ target,
        const float* __restrict__ scores, double* __restrict__ accs){
  __shared__ float ltg[TY+4][TX+4], lsc[TY+4][TX+4];
  __shared__ float rbuf[4][2];
  int b = blockIdx.z;
  int x0 = blockIdx.x*TX, y0 = blockIdx.y*TY;
  const float* tg = target + (size_t)b*HWsz;
  const float* sb = scores + (size_t)b*HWsz;
  const int W2 = TX+4, H2 = TY+4;
  for (int i = threadIdx.x; i < H2*W2; i += 256){
    int ly = i / W2, lx = i - ly*W2;
    int gy = y0 - 2 + ly, gx = x0 - 2 + lx;
    ltg[ly][lx] = (gy >= 0 && gy < HH && gx >= 0 && gx < WW) ? tg[(size_t)gy*WW + gx] : -1e30f;
    lsc[ly][lx] = sb[(size_t)refl(gy,HH)*WW + refl(gx,WW)];
  }
  __syncthreads();
  int tx = threadIdx.x & (TX-1), ty = threadIdx.x / TX;
  float m = -1e30f, S5 = 0.f;
  #pragma unroll
  for (int dy=0; dy<5; ++dy)
    #pragma unroll
    for (int dx=0; dx<5; ++dx){
      m = fmaxf(m, ltg[ty+dy][tx+dx]);
      S5 += lsc[ty+dy][tx+dx];
    }
  float tv = ltg[ty+2][tx+2];
  float sc = lsc[ty+2][tx+2];
  float tb = (tv > 0.f && tv == m) ? 1.f : 0.f;
  float pc = fminf(fmaxf(sc, 1e-12f), 1.0f - 1e-12f);
  float bce = -(tb*__logf(pc) + (1.f-tb)*__logf(1.f-pc));
  float lap = (S5 - sc)*(1.0f/48.0f) - 0.5f*sc;
  float extra = sc*__expf(-lap);
  bce = wave_sum(bce); extra = wave_sum(extra);
  int wave = threadIdx.x >> 6, lane = threadIdx.x & 63;
  if (lane == 0){ rbuf[wave][0] = bce; rbuf[wave][1] = extra; }
  __syncthreads();
  if (threadIdx.x == 0){
    int slot = (blockIdx.x + blockIdx.y*(WW/TX) + blockIdx.z*400) & (NSLOT-1);
    atomicAdd(&accs[(1*NSLOT + slot)*8], (double)(rbuf[0][0]+rbuf[1][0]+rbuf[2][0]+rbuf[3][0]));
    atomicAdd(&accs[(2*NSLOT + slot)*8], (double)(rbuf[0][1]+rbuf[1][1]+rbuf[2][1]+rbuf[3][1]));
  }
}

// ---------------- K10+K11 merged, 128x128 tiles, ticket-fused finalize ----------------
// grid (36, 1, 36). match: ti -> (mt,nt) triangular over 8 tiles of 128.
// distinction: flat = bx + 36*bz < 384. Last finishing block computes the final loss.
__global__ __launch_bounds__(256) void k_grams(const unsigned short* __restrict__ dbf,
        const float* __restrict__ xx, const float* __restrict__ points,
        const float* __restrict__ mproj, const unsigned char* __restrict__ mvis,
        double* __restrict__ accs, unsigned int* __restrict__ ticket,
        float* __restrict__ out){
  __shared__ float rbuf[4][4];
  __shared__ int lastFlag;
  int ab = blockIdx.z; int a = ab / BB, b = ab - a*BB;
  int ti = blockIdx.x;
  int mt = 0;
  while (ti >= 8 - mt){ ti -= 8 - mt; ++mt; }
  int nt = mt + ti;
  int tid = threadIdx.x;
  int wave = tid >> 6, lane = tid & 63;
  int wr = mt*128 + (wave&1)*64;
  int wc = nt*128 + (wave>>1)*64;
  int r = lane & 15, kg = lane >> 4;
  const unsigned short* descA = dbf + (size_t)a*NPTS*DD;
  const unsigned short* descB = dbf + (size_t)b*NPTS*DD;
  const float* xxa = xx + (size_t)a*NPTS;
  const float* xxb = xx + (size_t)b*NPTS;
  const float* pts = points + (size_t)b*NPTS*2;
  const float* mp  = mproj + (((size_t)a*BB+b)*NPTS)*2;
  const unsigned char* mv = mvis + ((size_t)a*BB+b)*NPTS;
  // ---- MFMA: 4x4 fragments, K=128 ----
  f32x4 acc[4][4] = {};
  #pragma unroll
  for (int ks = 0; ks < 4; ++ks){
    int ko = ks*32 + kg*8;
    bf16x8 af[4], bf[4];
    #pragma unroll
    for (int q = 0; q < 4; ++q){
      af[q] = *(const bf16x8*)(descA + (size_t)(wr+q*16+r)*DD + ko);
      bf[q] = *(const bf16x8*)(descB + (size_t)(wc+q*16+r)*DD + ko);
    }
    #pragma unroll
    for (int mi = 0; mi < 4; ++mi)
      #pragma unroll
      for (int ni = 0; ni < 4; ++ni)
        acc[mi][ni] = __builtin_amdgcn_mfma_f32_16x16x32_bf16(af[mi], bf[ni], acc[mi][ni], 0, 0, 0);
  }
  // ---- n-side prefetch ----
  float nxxv[4], ndx[4], ndy[4], ny2[4];
  #pragma unroll
  for (int ni = 0; ni < 4; ++ni){
    int n = wc + ni*16 + r;
    nxxv[ni] = xxb[n];
    float qx = mp[n*2+0], qy = mp[n*2+1];
    float dx = ((qx+1.f)*(float)(WW-1))*0.5f;
    float dy = ((qy+1.f)*(float)(HH-1))*0.5f;
    ndx[ni] = dx; ndy[ni] = dy;
    ny2[ni] = dx*dx + dy*dy;
  }
  float pos = 0.f, neg = 0.f, pcf = 0.f, ncf = 0.f;
  #pragma unroll
  for (int mi = 0; mi < 4; ++mi){
    #pragma unroll
    for (int j = 0; j < 4; ++j){
      int m = wr + mi*16 + 4*kg + j;
      if (!mv[m]) continue;
      float px = pts[m*2+0], py = pts[m*2+1];
      float sx = ((px+1.f)*(float)(WW-1))*0.5f;
      float sy = ((py+1.f)*(float)(HH-1))*0.5f;
      float x2 = sx*sx + sy*sy;
      float xm = xxa[m];
      #pragma unroll
      for (int ni = 0; ni < 4; ++ni){
        int n = wc + ni*16 + r;
        if (m >= n) continue;
        float dv = acc[mi][ni][j];
        float d2 = x2 + ny2[ni] - 2.f*(sx*ndx[ni] + sy*ndy[ni]);
        float p = dv * rsqrtf(fmaxf(xm * nxxv[ni], 1e-16f));
        if (d2 <= 1.0f){ pos += p; pcf += 1.f; }
        else           { neg += p; ncf += 1.f; }
      }
    }
  }
  pos = wave_sum(pos); neg = wave_sum(neg);
  pcf = wave_sum(pcf); ncf = wave_sum(ncf);
  if (lane == 0){ rbuf[wave][0] = pos; rbuf[wave][1] = neg; rbuf[wave][2] = pcf; rbuf[wave][3] = ncf; }
  __syncthreads();
  if (tid == 0){
    int slot = (blockIdx.x + blockIdx.z*8) & (NSLOT-1);
    atomicAdd(&accs[(3*NSLOT + slot)*8], (double)(rbuf[0][0]+rbuf[1][0]+rbuf[2][0]+rbuf[3][0]));
    atomicAdd(&accs[(4*NSLOT + slot)*8], (double)(rbuf[0][1]+rbuf[1][1]+rbuf[2][1]+rbuf[3][1]));
    atomicAdd(&accs[(5*NSLOT + slot)*8], (double)(rbuf[0][2]+rbuf[1][2]+rbuf[2][2]+rbuf[3][2]));
    atomicAdd(&accs[(6*NSLOT + slot)*8], (double)(rbuf[0][3]+rbuf[1][3]+rbuf[2][3]+rbuf[3][3]));
  }
  // ---- distinction tile (first 384 flat blocks), 128x128 ----
  int flat = blockIdx.x + 36*blockIdx.z;
  if (flat < 384){
    int db = flat >> 6;
    int dt = flat & 63;
    int wr2 = (dt >> 3)*128 + (wave&1)*64;
    int wc2 = (dt & 7)*128 + (wave>>1)*64;
    const unsigned short* descb = dbf + (size_t)db*NPTS*DD;
    const float* xb = xx + (size_t)db*NPTS;
    f32x4 ec[4][4] = {};
    #pragma unroll
    for (int ks = 0; ks < 4; ++ks){
      int ko = ks*32 + kg*8;
      bf16x8 af[4], bf[4];
      #pragma unroll
      for (int q = 0; q < 4; ++q){
        af[q] = *(const bf16x8*)(descb + (size_t)(wr2+q*16+r)*DD + ko);
        bf[q] = *(const bf16x8*)(descb + (size_t)(wc2+q*16+r)*DD + ko);
      }
      #pragma unroll
      for (int mi = 0; mi < 4; ++mi)
        #pragma unroll
        for (int ni = 0; ni < 4; ++ni)
          ec[mi][ni] = __builtin_amdgcn_mfma_f32_16x16x32_bf16(af[mi], bf[ni], ec[mi][ni], 0, 0, 0);
    }
    float xn[4];
    #pragma unroll
    for (int ni = 0; ni < 4; ++ni) xn[ni] = xb[wc2 + ni*16 + r];
    float local = 0.f;
    #pragma unroll
    for (int mi = 0; mi < 4; ++mi){
      #pragma unroll
      for (int j = 0; j < 4; ++j){
        float xm = xb[wr2 + mi*16 + 4*kg + j];
        #pragma unroll
        for (int ni = 0; ni < 4; ++ni)
          local += fmaxf(ec[mi][ni][j] * rsqrtf(fmaxf(xm*xn[ni], 1e-16f)), 0.f);
      }
    }
    local = wave_sum(local);
    __syncthreads();            // rbuf reuse
    if (lane == 0) rbuf[wave][0] = local;
    __syncthreads();
    if (tid == 0){
      int slot = flat & (NSLOT-1);
      atomicAdd(&accs[(0*NSLOT + slot)*8], (double)(rbuf[0][0]+rbuf[1][0]+rbuf[2][0]+rbuf[3][0]));
    }
  }
  // ---- ticket: last block computes the final loss ----
  if (tid == 0){
    __threadfence();
    unsigned int old = atomicAdd(ticket, 1u);
    lastFlag = (old == 36u*36u - 1u) ? 1 : 0;
  }
  __syncthreads();
  if (lastFlag && wave == 0){
    double tot[7];
    #pragma unroll
    for (int q = 0; q < 7; ++q)
      tot[q] = wave_sumd(__hip_atomic_load(&accs[((size_t)q*NSLOT + lane)*8],
                                           __ATOMIC_RELAXED, __HIP_MEMORY_SCOPE_AGENT));
    if (lane == 0){
      double distinction = tot[0] / (double)((long long)BB*NPTS*NPTS);
      double bce = tot[1] / (double)((long long)BB*HWsz);
      double extra = tot[2] / (double)((long long)BB*HWsz);
      double cornerness = bce + 10.0*extra;
      double pcd = tot[5] < 0.5 ? 1.0 : tot[5];
      double ncd = tot[6] < 0.5 ? 1.0 : tot[6];
      double pos_mean = tot[3] / pcd;
      double neg_mean = tot[4] / ncd;
      double match = 1.0 - pos_mean + neg_mean;
      out[0] = (float)(distinction + 0.5*cornerness + match);
    }
  }
}

extern "C" void kernel_launch(void* const* d_in, const int* in_sizes, int n_in,
                              void* d_out, int out_size, void* d_ws, size_t ws_size,
                              hipStream_t stream) {
  (void)in_sizes; (void)n_in; (void)out_size; (void)ws_size;
  const float* desc   = (const float*)d_in[0];
  const float* points = (const float*)d_in[1];
  const float* scores = (const float*)d_in[2];
  const float* depths = (const float*)d_in[3];
  const float* poses  = (const float*)d_in[4];
  const float* Km     = (const float*)d_in[5];
  const float* imgs   = (const float*)d_in[6];
  float* out = (float*)d_out;

  const size_t S = (size_t)BB*HWsz;
  float* resp   = (float*)d_ws;                                    // S
  float* target = resp + S;                                        // S
  unsigned long long* ckeys = (unsigned long long*)(target + S);   // BB*CAP*8
  unsigned int* ccnt = (unsigned int*)(ckeys + (size_t)BB*CAP);    // 8 uints (ccnt[0..5]; [6]=ticket)
  double* accs = (double*)(ccnt + 8);                              // 7*64*8 doubles
  float* cpts  = (float*)(accs + 7*NSLOT*8);                       // BB*NC*2
  float* cvals = cpts + (size_t)BB*NC*2;                           // BB*NC
  float* xx    = cvals + (size_t)BB*NC;                            // BB*NPTS
  float* mproj = xx + (size_t)BB*NPTS;                             // BB*BB*NPTS*2
  unsigned char* mvis = (unsigned char*)(mproj + (size_t)BB*BB*NPTS*2); // BB*BB*NPTS
  unsigned short* dbf = (unsigned short*)(mvis + (size_t)BB*BB*NPTS);   // bf16 desc

  dim3 blk(256);
  dim3 gtile(WW/TX, HH/TY, BB);

  hipMemsetAsync(target, 0,
      S*sizeof(float) +
      (size_t)BB*CAP*sizeof(unsigned long long) + 8*sizeof(unsigned int) +
      (size_t)7*NSLOT*8*sizeof(double), stream);

  // fused: image front-end (2400 blocks) + rownorm/proj (168 blocks)
  k_gftt<<<dim3(2400 + 168), blk, 0, stream>>>(imgs, resp, desc, xx, dbf,
                                               points, depths, poses, Km, mproj, mvis);
  k_nmsblk<<<gtile, blk, 0, stream>>>(resp, ckeys, ccnt);
  k_top500<<<dim3(BB), dim3(1024), 0, stream>>>(ckeys, cpts, cvals);
  {
    int n = BB*BB*NC;
    k_corner_scatter<<<dim3((n+255)/256), blk, 0, stream>>>(cpts, cvals, depths, poses, Km,
                                                            (unsigned int*)target);
  }
  k_score_reduce<<<gtile, blk, 0, stream>>>(target, scores, accs);
  k_grams<<<dim3(36, 1, BB*BB), blk, 0, stream>>>(dbf, xx, points, mproj, mvis, accs,
                                                  &ccnt[6], out);
}